// Round 6
// baseline (4267.460 us; speedup 1.0000x reference)
//
#include <hip/hip_runtime.h>
#include <hip/hip_bf16.h>

#define BATCH 64
#define SEQ 2048
#define IN_DIM 256
#define UNITS 256

typedef _Float16 half2_t __attribute__((ext_vector_type(2)));
typedef _Float16 half4_t __attribute__((ext_vector_type(4)));

__device__ __forceinline__ float fdot2(half2_t a, half2_t b, float c) {
#if __has_builtin(__builtin_amdgcn_fdot2)
    return __builtin_amdgcn_fdot2(a, b, c, false);
#else
    return c + (float)a[0] * (float)b[0] + (float)a[1] * (float)b[1];
#endif
}

// Lean barrier: producer-side LDS drain + hardware barrier.  NO vmcnt drain —
// outstanding global loads/stores stay in flight across the barrier (the
// compiler still inserts counted vmcnt waits before any USE of a load result).
__device__ __forceinline__ void lds_barrier() {
    asm volatile("s_waitcnt lgkmcnt(0)" ::: "memory");
    __builtin_amdgcn_s_barrier();
    asm volatile("" ::: "memory");
}

// ---------------------------------------------------------------------------
// Prep: transpose U_f, U_s (K x U, fp32) -> Ut (U x K, f16).
// ---------------------------------------------------------------------------
__global__ void prep_u(const float* __restrict__ Uf, const float* __restrict__ Us,
                       _Float16* __restrict__ Utf, _Float16* __restrict__ Uts) {
    int idx = blockIdx.x * 256 + threadIdx.x;   // 65536 total
    int k = idx >> 8;
    int u = idx & 255;
    Utf[u * 256 + k] = (_Float16)Uf[idx];
    Uts[u * 256 + k] = (_Float16)Us[idx];
}

// ---------------------------------------------------------------------------
// Projection GEMM: C[r][n] = X[r][:] @ W[:][n] + bias,  r in [0,131072)
// 64x64 output tile per workgroup, K chunked by 64.  blockIdx.y 0..3 -> W_f
// tiles (fp32 into d_out), 4..7 -> W_s tiles (f16 into ws).
// ---------------------------------------------------------------------------
__global__ __launch_bounds__(256) void proj_kernel(
    const float* __restrict__ X,
    const float* __restrict__ Wf, const float* __restrict__ bf,
    const float* __restrict__ Wsm, const float* __restrict__ bs,
    float* __restrict__ xf_out, _Float16* __restrict__ xs_out)
{
    __shared__ float Xs[64][65];    // 64 rows x 64 k, pad 65 -> conflict-free
    __shared__ float Wsh[64][68];   // 64 k x 64 n, pad 68 keeps 16B alignment

    const int tid = threadIdx.x;
    const int rt = blockIdx.x;
    const int ct = blockIdx.y;
    const int r0 = rt * 64;
    const bool is_f = ct < 4;
    const int c0 = (ct & 3) * 64;
    const float* W = is_f ? Wf : Wsm;
    const float* bias = is_f ? bf : bs;
    const int tx = tid & 15;   // row quad
    const int ty = tid >> 4;   // col quad

    float acc[4][4];
#pragma unroll
    for (int i = 0; i < 4; ++i)
#pragma unroll
        for (int j = 0; j < 4; ++j) acc[i][j] = 0.f;

    for (int kc = 0; kc < IN_DIM; kc += 64) {
        __syncthreads();
        // load X chunk: 64 rows x 64 k = 1024 float4
#pragma unroll
        for (int i = 0; i < 4; ++i) {
            int f = tid + i * 256;
            int row = f >> 4;          // 16 float4 per row
            int kq = f & 15;
            float4 v = *(const float4*)(X + (size_t)(r0 + row) * IN_DIM + kc + kq * 4);
            Xs[row][kq * 4 + 0] = v.x;
            Xs[row][kq * 4 + 1] = v.y;
            Xs[row][kq * 4 + 2] = v.z;
            Xs[row][kq * 4 + 3] = v.w;
        }
        // load W chunk: 64 k x 64 n
#pragma unroll
        for (int i = 0; i < 4; ++i) {
            int f = tid + i * 256;
            int kk = f >> 4;
            int n4 = f & 15;
            float4 v = *(const float4*)(W + (size_t)(kc + kk) * UNITS + c0 + n4 * 4);
            *(float4*)&Wsh[kk][n4 * 4] = v;
        }
        __syncthreads();
#pragma unroll 8
        for (int kk = 0; kk < 64; ++kk) {
            float a0 = Xs[tx * 4 + 0][kk];
            float a1 = Xs[tx * 4 + 1][kk];
            float a2 = Xs[tx * 4 + 2][kk];
            float a3 = Xs[tx * 4 + 3][kk];
            float4 bv = *(const float4*)&Wsh[kk][ty * 4];
            acc[0][0] += a0 * bv.x; acc[0][1] += a0 * bv.y; acc[0][2] += a0 * bv.z; acc[0][3] += a0 * bv.w;
            acc[1][0] += a1 * bv.x; acc[1][1] += a1 * bv.y; acc[1][2] += a1 * bv.z; acc[1][3] += a1 * bv.w;
            acc[2][0] += a2 * bv.x; acc[2][1] += a2 * bv.y; acc[2][2] += a2 * bv.z; acc[2][3] += a2 * bv.w;
            acc[3][0] += a3 * bv.x; acc[3][1] += a3 * bv.y; acc[3][2] += a3 * bv.z; acc[3][3] += a3 * bv.w;
        }
    }

#pragma unroll
    for (int i = 0; i < 4; ++i) {
        int r = r0 + tx * 4 + i;
        int n0 = c0 + ty * 4;
        if (is_f) {
            float4 v;
            v.x = acc[i][0] + bias[n0 + 0];
            v.y = acc[i][1] + bias[n0 + 1];
            v.z = acc[i][2] + bias[n0 + 2];
            v.w = acc[i][3] + bias[n0 + 3];
            *(float4*)(xf_out + (size_t)r * UNITS + n0) = v;
        } else {
#pragma unroll
            for (int j = 0; j < 4; ++j)
                xs_out[(size_t)r * UNITS + n0 + j] = (_Float16)(acc[i][j] + bias[n0 + j]);
        }
    }
}

// ---------------------------------------------------------------------------
// Recurrence: one workgroup (512 thr = 8 waves) per batch element.
// G-trick: thread covers 4 UNITS x 32 k, so each LDS h-read is amortized over
// 4 dot products -> h-broadcast LDS traffic drops 4x (256KB -> 64KB/step),
// which was the measured bottleneck (3072 of ~3480 cyc/step at 12cyc/b128).
//   lane: q = lane&7 (k-slice), g = lane>>3; units U0=w*32+g*4 .. U0+3.
//   k-chunks: c=0..3, k in [c*64+q*8, +8) -> wave's 8 distinct b128 addrs
//   (byte c*128+q*16) cover all 32 banks exactly once; 8-lane broadcast
//   groups are free.  Reduction over the 8 q-partners: shfl_xor 1,2,4.
// Gates/state/stores on q==0 lanes only (own 4 consecutive units; hreg[4],
// fg[4] in registers; b64 LDS writes; float4 global store, write-behind).
// 2 lean barriers/step; q0-only 2-deep prefetch of xf/xs.
// NOTE: __launch_bounds__(512, 1) — NOT (512,2).  The min-waves=2 variant
// caps VGPRs at 128 < live set -> scratch spilling, which produced
// replay-nondeterministic output under graph capture (round 5 tripwire).
// ---------------------------------------------------------------------------
__global__ __launch_bounds__(512, 1) void recur_kernel(
    float* xf_out,                       // aliases d_out: xf in, h out (no restrict!)
    const _Float16* __restrict__ xs16,   // [B][T][U]
    const _Float16* __restrict__ Utf,    // [U][K] f16
    const _Float16* __restrict__ Uts)    // [U][K] f16
{
    __shared__ __align__(16) _Float16 h2[256];
    __shared__ __align__(16) _Float16 g2[256];

    const int tid = threadIdx.x;
    const int lane = tid & 63;
    const int w = tid >> 6;          // wave 0..7
    const int q = lane & 7;          // k-slice index
    const int g = lane >> 3;         // unit-group within wave
    const int U0 = w * 32 + g * 4;   // 4 consecutive units owned
    const int b = blockIdx.x;

    union F4H { float4 f4; half2_t h[4]; };
    union F4A { float4 v; float a[4]; };

    // weights: uf[i][c][m] covers k = c*64+q*8+2m.. of column U0+i
    half2_t uf[4][4][4], us[4][4][4];
#pragma unroll
    for (int i = 0; i < 4; ++i) {
        const _Float16* pf = Utf + (size_t)(U0 + i) * 256;
        const _Float16* ps = Uts + (size_t)(U0 + i) * 256;
#pragma unroll
        for (int c = 0; c < 4; ++c) {
            F4H a; a.f4 = *(const float4*)(pf + c * 64 + q * 8);
            F4H d; d.f4 = *(const float4*)(ps + c * 64 + q * 8);
#pragma unroll
            for (int m = 0; m < 4; ++m) {
                uf[i][c][m] = a.h[m];
                us[i][c][m] = d.h[m];
            }
        }
    }

    float hreg[4] = {0.f, 0.f, 0.f, 0.f};
    float fg[4]   = {0.f, 0.f, 0.f, 0.f};
    if (q == 0) {
        half4_t z;
        z[0] = (_Float16)0.f; z[1] = (_Float16)0.f;
        z[2] = (_Float16)0.f; z[3] = (_Float16)0.f;
        *(half4_t*)(h2 + U0) = z;
    }
    __syncthreads();

    const size_t base = (size_t)b * SEQ * UNITS + U0;

    // 2-deep rolling prefetch (q0 lanes only); zero-init for determinism
    F4A xfp0, xfp1;
    half4_t xsp0, xsp1;
    xfp0.v = make_float4(0.f, 0.f, 0.f, 0.f);
    xfp1.v = make_float4(0.f, 0.f, 0.f, 0.f);
    xsp0 = half4_t{(_Float16)0.f, (_Float16)0.f, (_Float16)0.f, (_Float16)0.f};
    xsp1 = xsp0;
    if (q == 0) {
        xfp0.v = *(const float4*)(xf_out + base);
        xsp0   = *(const half4_t*)(xs16 + base);
        xfp1.v = *(const float4*)(xf_out + base + UNITS);
        xsp1   = *(const half4_t*)(xs16 + base + UNITS);
    }

    for (int t = 0; t < SEQ; ++t) {
        F4A xfp2; half4_t xsp2;
        xfp2.v = make_float4(0.f, 0.f, 0.f, 0.f);
        xsp2 = half4_t{(_Float16)0.f, (_Float16)0.f, (_Float16)0.f, (_Float16)0.f};
        if (q == 0 && t + 2 < SEQ) {
            xfp2.v = *(const float4*)(xf_out + base + (size_t)(t + 2) * UNITS);
            xsp2   = *(const half4_t*)(xs16 + base + (size_t)(t + 2) * UNITS);
        }

        // ---- phase A: acc[i] = h . Uf[:, U0+i] (partial over this thread's 32 k)
        float acc[4] = {0.f, 0.f, 0.f, 0.f};
        {
            const float4* hv4 = (const float4*)h2;
#pragma unroll
            for (int c = 0; c < 4; ++c) {
                F4H hh; hh.f4 = hv4[c * 8 + q];   // byte c*128 + q*16
#pragma unroll
                for (int i = 0; i < 4; ++i) {
                    acc[i] = fdot2(uf[i][c][0], hh.h[0], acc[i]);
                    acc[i] = fdot2(uf[i][c][1], hh.h[1], acc[i]);
                    acc[i] = fdot2(uf[i][c][2], hh.h[2], acc[i]);
                    acc[i] = fdot2(uf[i][c][3], hh.h[3], acc[i]);
                }
            }
        }
#pragma unroll
        for (int i = 0; i < 4; ++i) {
            acc[i] += __shfl_xor(acc[i], 1);
            acc[i] += __shfl_xor(acc[i], 2);
            acc[i] += __shfl_xor(acc[i], 4);
        }
        if (q == 0) {
            half4_t gv;
#pragma unroll
            for (int i = 0; i < 4; ++i) {
                float fv = 1.f / (1.f + __expf(-(xfp0.a[i] + acc[i])));
                fg[i] = fv;
                gv[i] = (_Float16)(fv * hreg[i]);
            }
            *(half4_t*)(g2 + U0) = gv;
        }
        lds_barrier();

        // ---- phase B: bcc[i] = (f*h) . Us[:, U0+i]
        float bcc[4] = {0.f, 0.f, 0.f, 0.f};
        {
            const float4* gv4 = (const float4*)g2;
#pragma unroll
            for (int c = 0; c < 4; ++c) {
                F4H hh; hh.f4 = gv4[c * 8 + q];
#pragma unroll
                for (int i = 0; i < 4; ++i) {
                    bcc[i] = fdot2(us[i][c][0], hh.h[0], bcc[i]);
                    bcc[i] = fdot2(us[i][c][1], hh.h[1], bcc[i]);
                    bcc[i] = fdot2(us[i][c][2], hh.h[2], bcc[i]);
                    bcc[i] = fdot2(us[i][c][3], hh.h[3], bcc[i]);
                }
            }
        }
#pragma unroll
        for (int i = 0; i < 4; ++i) {
            bcc[i] += __shfl_xor(bcc[i], 1);
            bcc[i] += __shfl_xor(bcc[i], 2);
            bcc[i] += __shfl_xor(bcc[i], 4);
        }
        if (q == 0) {
            half4_t hv; F4A outv;
#pragma unroll
            for (int i = 0; i < 4; ++i) {
                float z = (float)xsp0[i] + bcc[i];
                z = fminf(fmaxf(z, -15.f), 15.f);
                float e = __expf(2.f * z);
                float s = (e - 1.f) / (e + 1.f);
                float hn = (1.f - fg[i]) * hreg[i] + fg[i] * s;
                hreg[i] = hn;
                hv[i] = (_Float16)hn;
                outv.a[i] = hn;
            }
            *(half4_t*)(h2 + U0) = hv;
            *(float4*)(xf_out + base + (size_t)t * UNITS) = outv.v;  // write-behind
        }
        lds_barrier();

        xfp0 = xfp1; xfp1 = xfp2;
        xsp0 = xsp1; xsp1 = xsp2;
    }
}

extern "C" void kernel_launch(void* const* d_in, const int* in_sizes, int n_in,
                              void* d_out, int out_size, void* d_ws, size_t ws_size,
                              hipStream_t stream) {
    (void)in_sizes; (void)n_in; (void)out_size; (void)ws_size;

    const float* X   = (const float*)d_in[0];
    const float* Wf  = (const float*)d_in[1];
    const float* Uf  = (const float*)d_in[2];
    const float* bf  = (const float*)d_in[3];
    const float* Wsm = (const float*)d_in[4];
    const float* Us  = (const float*)d_in[5];
    const float* bs  = (const float*)d_in[6];
    float* out = (float*)d_out;

    // ws layout: xs16 (64 MB) | Utf (128 KB) | Uts (128 KB)
    _Float16* xs16 = (_Float16*)d_ws;
    _Float16* Utf  = xs16 + (size_t)BATCH * SEQ * UNITS;
    _Float16* Uts  = Utf + 256 * 256;

    prep_u<<<256, 256, 0, stream>>>(Uf, Us, Utf, Uts);
    proj_kernel<<<dim3(BATCH * SEQ / 64, 8), 256, 0, stream>>>(X, Wf, bf, Wsm, bs, out, xs16);
    recur_kernel<<<BATCH, 512, 0, stream>>>(out, xs16, Utf, Uts);
}